// Round 5
// baseline (70.225 us; speedup 1.0000x reference)
//
#include <hip/hip_runtime.h>

// RandWarpAug: B=512, C=12, T=4096, DS=4, STEPS=7, KS=51
// in[0] = source   [512,12,4096] f32
// in[1] = flow_mag [1]           f32
// in[2] = noise    [512,1,4096]  f32
// in[3] = smooth_kernel [51]     f32
// out   = [512,12,4096] f32

#define BB 512
#define CC 12
#define TT 4096
#define TD 1024
#define KS 51
#define NT 1024

typedef float f32x4 __attribute__((ext_vector_type(4)));

struct WarpW { int y0c, y1c; float w0, w1; };

// Faithful replication of reference warp_1d coordinate math for one sample.
template <int TLEN>
__device__ __forceinline__ WarpW warp_weights(int t, float flow) {
    const float tm1 = (float)(TLEN - 1);
    float nl = (float)t + flow;                 // new_locs
    float v  = 2.0f * (nl / tm1 - 0.5f);        // normalized
    float ix = (v + 1.0f) * 0.5f;               // W=2 -> (W-1)=1
    float iy = ix * tm1;
    float x0 = floorf(ix);
    float fx = ix - x0;
    int   x0i = (int)x0;
    float m0 = (x0i >= 0 && x0i <= 1) ? 1.0f : 0.0f;
    float m1 = (x0i + 1 >= 0 && x0i + 1 <= 1) ? 1.0f : 0.0f;
    float xw = (1.0f - fx) * m0 + fx * m1;
    float y0 = floorf(iy);
    float fy = iy - y0;
    int   y0i = (int)y0;
    int   y1i = y0i + 1;
    float vy0 = (y0i >= 0 && y0i < TLEN) ? 1.0f : 0.0f;
    float vy1 = (y1i >= 0 && y1i < TLEN) ? 1.0f : 0.0f;
    WarpW r;
    r.y0c = min(max(y0i, 0), TLEN - 1);
    r.y1c = min(max(y1i, 0), TLEN - 1);
    r.w0 = xw * (1.0f - fy) * vy0;
    r.w1 = xw * fy * vy1;
    return r;
}

extern "C" __global__ void __launch_bounds__(NT)
rand_warp_aug_kernel(const float* __restrict__ source,
                     const float* __restrict__ flow_mag,
                     const float* __restrict__ noise,
                     const float* __restrict__ gk,
                     float* __restrict__ out) {
    __shared__ float vecA[TD];
    __shared__ float vecB[TD];
    __shared__ float pf_up[TT];
    __shared__ float pf_sm[TT];
    __shared__ float g[KS];

    const int b   = blockIdx.x;
    const int tid = threadIdx.x;
    const float fm = flow_mag[0];

    // ---- phase 1: flow_field = fm*noise; downsample x4 (w=0.5 at 4i+1,4i+2);
    //      * 0.25 (resize factor<1) * 1/128 (VecInt scaling); vec4 noise load ----
    const f32x4* nrow4 = (const f32x4*)(noise + (size_t)b * TT);
    if (tid < TD) {
        f32x4 nv = nrow4[tid];
        float x1 = fm * nv.y;
        float x2 = fm * nv.z;
        vecA[tid] = (x1 * 0.5f + x2 * 0.5f) * (0.25f * 0.0078125f);
    }
    if (tid < KS) g[tid] = gk[tid];
    __syncthreads();

    // ---- phase 2: VecInt scaling-and-squaring, 7 steps, Tlen=1024 ----
    float* cur = vecA;
    float* nxt = vecB;
#pragma unroll 1
    for (int s = 0; s < 7; ++s) {
        if (tid < TD) {
            float fl = cur[tid];
            WarpW w = warp_weights<TD>(tid, fl);
            nxt[tid] = fl + (w.w0 * cur[w.y0c] + w.w1 * cur[w.y1c]);
        }
        __syncthreads();
        float* tmp = cur; cur = nxt; nxt = tmp;
    }
    // final vec is in `cur`

    // ---- phase 3: upsample x4 with magnitude rescale (x4) ----
#pragma unroll
    for (int jj = 0; jj < TT / NT; ++jj) {
        int j = tid + jj * NT;
        float srcp = ((float)j + 0.5f) * 0.25f - 0.5f;
        srcp = fminf(fmaxf(srcp, 0.0f), (float)(TD - 1));
        float flp = floorf(srcp);
        int   i0  = (int)flp;
        int   i1  = min(i0 + 1, TD - 1);
        float w   = srcp - flp;
        float a0  = 4.0f * cur[i0];
        float a1  = 4.0f * cur[i1];
        pf_up[j] = a0 * (1.0f - w) + a1 * w;
    }
    __syncthreads();

    // ---- phase 4: 51-tap conv (zero pad), stride-1 LDS reads (conflict-free) ----
#pragma unroll
    for (int tt = 0; tt < TT / NT; ++tt) {
        int t = tid + tt * NT;
        float acc = 0.0f;
        int lo = t - (KS - 1) / 2;
#pragma unroll
        for (int k = 0; k < KS; ++k) {
            int idx = lo + k;
            float xv = (idx >= 0 && idx < TT) ? pf_up[idx] : 0.0f;
            acc += xv * g[k];
        }
        pf_sm[t] = acc;
    }
    __syncthreads();

    // ---- phase 5: warp of source, 4 consecutive t per thread, vec4 nt stores ----
    const int t0 = tid * 4;
    f32x4 fl4 = *(const f32x4*)&pf_sm[t0];     // ds_read_b128
    WarpW w[4];
    w[0] = warp_weights<TT>(t0 + 0, fl4.x);
    w[1] = warp_weights<TT>(t0 + 1, fl4.y);
    w[2] = warp_weights<TT>(t0 + 2, fl4.z);
    w[3] = warp_weights<TT>(t0 + 3, fl4.w);

    const float* sbase = source + (size_t)b * CC * TT;
    float*       obase = out    + (size_t)b * CC * TT;
#pragma unroll
    for (int c = 0; c < CC; ++c) {
        const float* srow = sbase + (size_t)c * TT;
        f32x4 o;
        o.x = w[0].w0 * srow[w[0].y0c] + w[0].w1 * srow[w[0].y1c];
        o.y = w[1].w0 * srow[w[1].y0c] + w[1].w1 * srow[w[1].y1c];
        o.z = w[2].w0 * srow[w[2].y0c] + w[2].w1 * srow[w[2].y1c];
        o.w = w[3].w0 * srow[w[3].y0c] + w[3].w1 * srow[w[3].y1c];
        f32x4* orow4 = (f32x4*)(obase + (size_t)c * TT);
        __builtin_nontemporal_store(o, orow4 + tid);
    }
}

extern "C" void kernel_launch(void* const* d_in, const int* in_sizes, int n_in,
                              void* d_out, int out_size, void* d_ws, size_t ws_size,
                              hipStream_t stream) {
    const float* source   = (const float*)d_in[0];
    const float* flow_mag = (const float*)d_in[1];
    const float* noise    = (const float*)d_in[2];
    const float* gk       = (const float*)d_in[3];
    float* out = (float*)d_out;

    rand_warp_aug_kernel<<<BB, NT, 0, stream>>>(source, flow_mag, noise, gk, out);
}

// Round 6
// 55.396 us; speedup vs baseline: 1.2677x; 1.2677x over previous
//
#include <hip/hip_runtime.h>

// RandWarpAug: B=512, C=12, T=4096, DS=4, STEPS=7, KS=51
// in[0] = source   [512,12,4096] f32
// in[1] = flow_mag [1]           f32
// in[2] = noise    [512,1,4096]  f32
// in[3] = smooth_kernel [51]     f32
// out   = [512,12,4096] f32

#define BB 512
#define CC 12
#define TT 4096
#define TD 1024
#define KS 51
#define NT 1024
#define NJ 17
#define J0 (-8)
#define T_LO 32
#define T_HI 4063

typedef float f32x4 __attribute__((ext_vector_type(4)));

struct WarpW { int y0c, y1c; float w0, w1; };

// Faithful replication of reference warp_1d coordinate math for one sample.
template <int TLEN>
__device__ __forceinline__ WarpW warp_weights(int t, float flow) {
    const float tm1 = (float)(TLEN - 1);
    float nl = (float)t + flow;                 // new_locs
    float v  = 2.0f * (nl / tm1 - 0.5f);        // normalized
    float ix = (v + 1.0f) * 0.5f;               // W=2 -> (W-1)=1
    float iy = ix * tm1;
    float x0 = floorf(ix);
    float fx = ix - x0;
    int   x0i = (int)x0;
    float m0 = (x0i >= 0 && x0i <= 1) ? 1.0f : 0.0f;
    float m1 = (x0i + 1 >= 0 && x0i + 1 <= 1) ? 1.0f : 0.0f;
    float xw = (1.0f - fx) * m0 + fx * m1;
    float y0 = floorf(iy);
    float fy = iy - y0;
    int   y0i = (int)y0;
    int   y1i = y0i + 1;
    float vy0 = (y0i >= 0 && y0i < TLEN) ? 1.0f : 0.0f;
    float vy1 = (y1i >= 0 && y1i < TLEN) ? 1.0f : 0.0f;
    WarpW r;
    r.y0c = min(max(y0i, 0), TLEN - 1);
    r.y1c = min(max(y1i, 0), TLEN - 1);
    r.w0 = xw * (1.0f - fy) * vy0;
    r.w1 = xw * fy * vy1;
    return r;
}

// Boundary path: conv(upsample(vec)) computed directly (zero-pad + clamp).
__device__ __forceinline__ float conv_direct(const float* __restrict__ vec,
                                             const float* __restrict__ g, int t) {
    float acc = 0.0f;
    for (int k = 0; k < KS; ++k) {
        int s = t + k - 25;
        if (s < 0 || s >= TT) continue;
        float srcp = 0.25f * (float)s - 0.375f;
        srcp = fminf(fmaxf(srcp, 0.0f), (float)(TD - 1));
        float flp = floorf(srcp);
        int i0 = (int)flp;
        int i1 = min(i0 + 1, TD - 1);
        float w = srcp - flp;
        acc += g[k] * 4.0f * ((1.0f - w) * vec[i0] + w * vec[i1]);
    }
    return acc;
}

extern "C" __global__ void __launch_bounds__(NT)
rand_warp_aug_kernel(const float* __restrict__ source,
                     const float* __restrict__ flow_mag,
                     const float* __restrict__ noise,
                     const float* __restrict__ gk,
                     float* __restrict__ out) {
    __shared__ float vecA[TD];
    __shared__ float vecB[TD];
    __shared__ float g[KS];
    __shared__ float wtab[NJ][4];   // [j][p], p = t%4 fastest (bank-friendly)

    const int b   = blockIdx.x;
    const int tid = threadIdx.x;
    const float fm = flow_mag[0];

    // ---- phase 1: flow_field = fm*noise; downsample x4 (w=0.5 at 4i+1,4i+2);
    //      * 0.25 (resize factor<1) * 1/128 (VecInt scaling) ----
    const f32x4* nrow4 = (const f32x4*)(noise + (size_t)b * TT);
    {
        f32x4 nv = nrow4[tid];
        float x1 = fm * nv.y;
        float x2 = fm * nv.z;
        vecA[tid] = (x1 * 0.5f + x2 * 0.5f) * (0.25f * 0.0078125f);
    }
    if (tid < KS) g[tid] = gk[tid];
    __syncthreads();

    // ---- build fused conv51 ∘ upsample4 stencil table (interior form) ----
    // out[4T+p] = 4 * sum_j wtab[j][p] * vec[T + j + J0]
    if (tid < 4 * NJ) {
        int p = tid / NJ;
        int j = tid % NJ + J0;
        float acc = 0.0f;
        for (int k = 0; k < KS; ++k) {
            int q = p + k - 25;
            int d = (q >= 0) ? (q >> 2) : -((-q + 3) >> 2);  // floor(q/4)
            int r = q - 4 * d;
            float c = 0.0f;
            if (r == 0)      { if (j == d - 1) c = 0.375f; else if (j == d) c = 0.625f; }
            else if (r == 1) { if (j == d - 1) c = 0.125f; else if (j == d) c = 0.875f; }
            else if (r == 2) { if (j == d)     c = 0.875f; else if (j == d + 1) c = 0.125f; }
            else             { if (j == d)     c = 0.625f; else if (j == d + 1) c = 0.375f; }
            acc += g[k] * c;
        }
        wtab[tid % NJ][p] = 4.0f * acc;
    }
    // (visible after the first VecInt barrier below)

    // ---- phase 2: VecInt scaling-and-squaring, 7 steps, Tlen=1024 ----
    float* cur = vecA;
    float* nxt = vecB;
#pragma unroll 1
    for (int s = 0; s < 7; ++s) {
        {
            float fl = cur[tid];
            WarpW w = warp_weights<TD>(tid, fl);
            nxt[tid] = fl + (w.w0 * cur[w.y0c] + w.w1 * cur[w.y1c]);
        }
        __syncthreads();
        float* tmp = cur; cur = nxt; nxt = tmp;
    }
    // final vec is in `cur`

    // ---- phase 3: fused upsample+conv via 17-tap coarse stencil ----
    const int p  = tid & 3;
    const int Tb = tid >> 2;          // coarse base for tt=0
    float pf[4];
    {
        float wreg;
        float a0 = 0.0f, a1 = 0.0f, a2 = 0.0f, a3 = 0.0f;
#pragma unroll
        for (int j = 0; j < NJ; ++j) {
            wreg = wtab[j][p];
            int base = Tb + j + J0;
            a0 += wreg * cur[base];
            a1 += wreg * cur[base + 256];
            a2 += wreg * cur[base + 512];
            a3 += wreg * cur[base + 768];
        }
        pf[0] = a0; pf[1] = a1; pf[2] = a2; pf[3] = a3;
    }
    // boundary overrides (zero-pad / clamp region): t<T_LO or t>T_HI
    if (tid < T_LO)            pf[0] = conv_direct(cur, g, tid);
    if (tid >= NT - (TT - 1 - T_HI)) pf[3] = conv_direct(cur, g, tid + 3 * NT);

    // ---- phase 4: warp of source; t stride-1 across lanes (coalesced) ----
    const float* sbase = source + (size_t)b * CC * TT;
    float*       obase = out    + (size_t)b * CC * TT;
#pragma unroll
    for (int tt = 0; tt < TT / NT; ++tt) {
        int t = tid + tt * NT;
        WarpW w = warp_weights<TT>(t, pf[tt]);
#pragma unroll
        for (int c = 0; c < CC; ++c) {
            const float* srow = sbase + (size_t)c * TT;
            float g0 = srow[w.y0c];
            float g1 = srow[w.y1c];
            obase[(size_t)c * TT + t] = w.w0 * g0 + w.w1 * g1;
        }
    }
}

extern "C" void kernel_launch(void* const* d_in, const int* in_sizes, int n_in,
                              void* d_out, int out_size, void* d_ws, size_t ws_size,
                              hipStream_t stream) {
    const float* source   = (const float*)d_in[0];
    const float* flow_mag = (const float*)d_in[1];
    const float* noise    = (const float*)d_in[2];
    const float* gk       = (const float*)d_in[3];
    float* out = (float*)d_out;

    rand_warp_aug_kernel<<<BB, NT, 0, stream>>>(source, flow_mag, noise, gk, out);
}

// Round 7
// 54.227 us; speedup vs baseline: 1.2950x; 1.0216x over previous
//
#include <hip/hip_runtime.h>

// RandWarpAug: B=512, C=12, T=4096, DS=4, STEPS=7, KS=51
// in[0] = source   [512,12,4096] f32
// in[1] = flow_mag [1]           f32
// in[2] = noise    [512,1,4096]  f32
// in[3] = smooth_kernel [51]     f32
// out   = [512,12,4096] f32

#define BB 512
#define CC 12
#define TT 4096
#define TD 1024
#define KS 51
#define NT 1024
#define NJ 17
#define J0 (-8)
#define T_LO 32
#define T_HI 4063

typedef float f32x4 __attribute__((ext_vector_type(4)));
typedef float f32x2 __attribute__((ext_vector_type(2), aligned(4)));

struct WarpW { int y0c, y1c; float w0, w1; };
struct WarpP { int addr, o0, o1; float w0, w1; };

// Faithful replication of reference warp_1d coordinate math for one sample.
template <int TLEN>
__device__ __forceinline__ WarpW warp_weights(int t, float flow) {
    const float tm1 = (float)(TLEN - 1);
    float nl = (float)t + flow;                 // new_locs
    float v  = 2.0f * (nl / tm1 - 0.5f);        // normalized
    float ix = (v + 1.0f) * 0.5f;               // W=2 -> (W-1)=1
    float iy = ix * tm1;
    float x0 = floorf(ix);
    float fx = ix - x0;
    int   x0i = (int)x0;
    float m0 = (x0i >= 0 && x0i <= 1) ? 1.0f : 0.0f;
    float m1 = (x0i + 1 >= 0 && x0i + 1 <= 1) ? 1.0f : 0.0f;
    float xw = (1.0f - fx) * m0 + fx * m1;
    float y0 = floorf(iy);
    float fy = iy - y0;
    int   y0i = (int)y0;
    int   y1i = y0i + 1;
    float vy0 = (y0i >= 0 && y0i < TLEN) ? 1.0f : 0.0f;
    float vy1 = (y1i >= 0 && y1i < TLEN) ? 1.0f : 0.0f;
    WarpW r;
    r.y0c = min(max(y0i, 0), TLEN - 1);
    r.y1c = min(max(y1i, 0), TLEN - 1);
    r.w0 = xw * (1.0f - fy) * vy0;
    r.w1 = xw * fy * vy1;
    return r;
}

// Packed variant for the streaming phase: one dwordx2 base address + selects.
// Where the select would pick the "wrong" element, the matching weight is 0.
template <int TLEN>
__device__ __forceinline__ WarpP warp_pack(int t, float flow) {
    const float tm1 = (float)(TLEN - 1);
    float nl = (float)t + flow;
    float v  = 2.0f * (nl / tm1 - 0.5f);
    float ix = (v + 1.0f) * 0.5f;
    float iy = ix * tm1;
    float x0 = floorf(ix);
    float fx = ix - x0;
    int   x0i = (int)x0;
    float m0 = (x0i >= 0 && x0i <= 1) ? 1.0f : 0.0f;
    float m1 = (x0i + 1 >= 0 && x0i + 1 <= 1) ? 1.0f : 0.0f;
    float xw = (1.0f - fx) * m0 + fx * m1;
    float y0 = floorf(iy);
    float fy = iy - y0;
    int   y0i = (int)y0;
    int   y1i = y0i + 1;
    float vy0 = (y0i >= 0 && y0i < TLEN) ? 1.0f : 0.0f;
    float vy1 = (y1i >= 0 && y1i < TLEN) ? 1.0f : 0.0f;
    int y0c = min(max(y0i, 0), TLEN - 1);
    int y1c = min(max(y1i, 0), TLEN - 1);
    WarpP r;
    r.addr = min(max(y0i, 0), TLEN - 2);
    r.o0   = y0c - r.addr;        // 0 or 1
    r.o1   = y1c - r.addr;        // 0 or 1
    r.w0   = xw * (1.0f - fy) * vy0;
    r.w1   = xw * fy * vy1;
    return r;
}

// Boundary path: conv(upsample(vec)) computed directly (zero-pad + clamp).
__device__ __forceinline__ float conv_direct(const float* __restrict__ vec,
                                             const float* __restrict__ g, int t) {
    float acc = 0.0f;
    for (int k = 0; k < KS; ++k) {
        int s = t + k - 25;
        if (s < 0 || s >= TT) continue;
        float srcp = 0.25f * (float)s - 0.375f;
        srcp = fminf(fmaxf(srcp, 0.0f), (float)(TD - 1));
        float flp = floorf(srcp);
        int i0 = (int)flp;
        int i1 = min(i0 + 1, TD - 1);
        float w = srcp - flp;
        acc += g[k] * 4.0f * ((1.0f - w) * vec[i0] + w * vec[i1]);
    }
    return acc;
}

extern "C" __global__ void __launch_bounds__(NT)
rand_warp_aug_kernel(const float* __restrict__ source,
                     const float* __restrict__ flow_mag,
                     const float* __restrict__ noise,
                     const float* __restrict__ gk,
                     float* __restrict__ out) {
    __shared__ float vecA[TD];
    __shared__ float vecB[TD];
    __shared__ float g[KS];
    __shared__ float wtab[NJ][4];   // [j][p], p = t%4 fastest

    const int b   = blockIdx.x;
    const int tid = threadIdx.x;
    const float fm = flow_mag[0];

    // ---- phase 1: flow_field = fm*noise; downsample x4; *0.25 * 1/128 ----
    const f32x4* nrow4 = (const f32x4*)(noise + (size_t)b * TT);
    {
        f32x4 nv = nrow4[tid];
        float x1 = fm * nv.y;
        float x2 = fm * nv.z;
        vecA[tid] = (x1 * 0.5f + x2 * 0.5f) * (0.25f * 0.0078125f);
    }
    if (tid < KS) g[tid] = gk[tid];
    __syncthreads();

    // ---- build fused conv51 ∘ upsample4 stencil table (interior form) ----
    if (tid < 4 * NJ) {
        int p = tid / NJ;
        int j = tid % NJ + J0;
        float acc = 0.0f;
        for (int k = 0; k < KS; ++k) {
            int q = p + k - 25;
            int d = (q >= 0) ? (q >> 2) : -((-q + 3) >> 2);  // floor(q/4)
            int r = q - 4 * d;
            float c = 0.0f;
            if (r == 0)      { if (j == d - 1) c = 0.375f; else if (j == d) c = 0.625f; }
            else if (r == 1) { if (j == d - 1) c = 0.125f; else if (j == d) c = 0.875f; }
            else if (r == 2) { if (j == d)     c = 0.875f; else if (j == d + 1) c = 0.125f; }
            else             { if (j == d)     c = 0.625f; else if (j == d + 1) c = 0.375f; }
            acc += g[k] * c;
        }
        wtab[tid % NJ][p] = 4.0f * acc;
    }
    // (visible after the first VecInt barrier below)

    // ---- phase 2: VecInt scaling-and-squaring, 7 steps, Tlen=1024 ----
    float* cur = vecA;
    float* nxt = vecB;
#pragma unroll 1
    for (int s = 0; s < 7; ++s) {
        {
            float fl = cur[tid];
            WarpW w = warp_weights<TD>(tid, fl);
            nxt[tid] = fl + (w.w0 * cur[w.y0c] + w.w1 * cur[w.y1c]);
        }
        __syncthreads();
        float* tmp = cur; cur = nxt; nxt = tmp;
    }
    // final vec is in `cur`

    // ---- phase 3: fused upsample+conv via 17-tap coarse stencil ----
    const int p  = tid & 3;
    const int Tb = tid >> 2;
    float pf[4];
    {
        float a0 = 0.0f, a1 = 0.0f, a2 = 0.0f, a3 = 0.0f;
#pragma unroll
        for (int j = 0; j < NJ; ++j) {
            float wreg = wtab[j][p];
            int base = Tb + j + J0;
            a0 += wreg * cur[base];
            a1 += wreg * cur[base + 256];
            a2 += wreg * cur[base + 512];
            a3 += wreg * cur[base + 768];
        }
        pf[0] = a0; pf[1] = a1; pf[2] = a2; pf[3] = a3;
    }
    if (tid < T_LO)                  pf[0] = conv_direct(cur, g, tid);
    if (tid >= NT - (TT - 1 - T_HI)) pf[3] = conv_direct(cur, g, tid + 3 * NT);

    // ---- phase 4: warp of source; t stride-1 across lanes; dwordx2 gathers ----
    const float* sbase = source + (size_t)b * CC * TT;
    float*       obase = out    + (size_t)b * CC * TT;
#pragma unroll
    for (int tt = 0; tt < TT / NT; ++tt) {
        int t = tid + tt * NT;
        WarpP w = warp_pack<TT>(t, pf[tt]);
#pragma unroll
        for (int c = 0; c < CC; ++c) {
            const float* srow = sbase + (size_t)c * TT;
            f32x2 v = *(const f32x2*)(srow + w.addr);
            float g0 = w.o0 ? v.y : v.x;
            float g1 = w.o1 ? v.y : v.x;
            float o = w.w0 * g0 + w.w1 * g1;
            __builtin_nontemporal_store(o, obase + (size_t)c * TT + t);
        }
    }
}

extern "C" void kernel_launch(void* const* d_in, const int* in_sizes, int n_in,
                              void* d_out, int out_size, void* d_ws, size_t ws_size,
                              hipStream_t stream) {
    const float* source   = (const float*)d_in[0];
    const float* flow_mag = (const float*)d_in[1];
    const float* noise    = (const float*)d_in[2];
    const float* gk       = (const float*)d_in[3];
    float* out = (float*)d_out;

    rand_warp_aug_kernel<<<BB, NT, 0, stream>>>(source, flow_mag, noise, gk, out);
}